// Round 1
// baseline (1837.391 us; speedup 1.0000x reference)
//
#include <hip/hip_runtime.h>
#include <hip/hip_bf16.h>
#include <math.h>

#define S 16
#define L 4096      // S^3
#define NC 64
#define BZ 4

// ---------------------------------------------------------------------------
// Shared helper: 3x3x3 ones box filter (zero padded) on a 16^3 cube in LDS.
// bufA holds input; bufB is scratch; result returned per-thread: thread
// (x = tid>>4, y = tid&15) gets its full z-line in out[16].
// bufA is clobbered. Ends with a sync.
// ---------------------------------------------------------------------------
__device__ void box3_16cube(float* bufA, float* bufB, int tid, float out[16]) {
    int x = tid >> 4, y = tid & 15;
    float t[16];
    // z pass (own line only)
    float* r = bufA + x * 256 + y * 16;
    {
        float line[16];
        for (int z = 0; z < 16; z++) line[z] = r[z];
        for (int z = 0; z < 16; z++) {
            float s = line[z];
            if (z > 0)  s += line[z - 1];
            if (z < 15) s += line[z + 1];
            t[z] = s;
        }
    }
    float* w = bufB + x * 256 + y * 16;
    for (int z = 0; z < 16; z++) w[z] = t[z];
    __syncthreads();
    // y pass: read bufB
    for (int z = 0; z < 16; z++) {
        float s = bufB[x * 256 + y * 16 + z];
        if (y > 0)  s += bufB[x * 256 + (y - 1) * 16 + z];
        if (y < 15) s += bufB[x * 256 + (y + 1) * 16 + z];
        t[z] = s;
    }
    __syncthreads();
    float* w2 = bufA + x * 256 + y * 16;
    for (int z = 0; z < 16; z++) w2[z] = t[z];
    __syncthreads();
    // x pass: read bufA
    for (int z = 0; z < 16; z++) {
        float s = bufA[x * 256 + y * 16 + z];
        if (x > 0)  s += bufA[(x - 1) * 256 + y * 16 + z];
        if (x < 15) s += bufA[(x + 1) * 256 + y * 16 + z];
        out[z] = s;
    }
    __syncthreads();
}

// ---------------------------------------------------------------------------
// K1: per-position prep for all samples.
//   bg = fm * (1-mask); channel sums: sfm=sum_c fm, sbg=sum_c bg, qbg=sum_c bg^2
// ---------------------------------------------------------------------------
__global__ void k_prep(const float* __restrict__ fm, const float* __restrict__ mask,
                       float* __restrict__ bg, float* __restrict__ sfm,
                       float* __restrict__ sbg, float* __restrict__ qbg) {
    int b = blockIdx.y;
    int p = blockIdx.x * 256 + threadIdx.x;
    float m = mask[b * L + p];
    float w = 1.f - m;
    float s_f = 0.f, s_b = 0.f, q_b = 0.f;
    const float* fmb = fm + (size_t)b * NC * L + p;
    float* bgb = bg + (size_t)b * NC * L + p;
    for (int c = 0; c < NC; c++) {
        float f = fmb[(size_t)c * L];
        float g = f * w;
        bgb[(size_t)c * L] = g;
        s_f += f; s_b += g; q_b += g * g;
    }
    sfm[b * L + p] = s_f;
    sbg[b * L + p] = s_b;
    qbg[b * L + p] = q_b;
}

// ---------------------------------------------------------------------------
// K2: per-sample patch-norm stats + S2fm.
//   Q = box3(qbg); Sb = box3(sbg); inv_norm = rsqrt(Q + 2e-7*Sb + 1728e-14)
//   S2fm = box3(box3(sfm))
// ---------------------------------------------------------------------------
__global__ void k_stats(const float* __restrict__ sfm, const float* __restrict__ sbg,
                        const float* __restrict__ qbg,
                        float* __restrict__ invn, float* __restrict__ s2fm) {
    __shared__ float A[4096];
    __shared__ float Bf[4096];
    int b = blockIdx.x;
    int tid = threadIdx.x;
    int x = tid >> 4, y = tid & 15;
    float Q[16], Sb[16], r[16];

    for (int i = tid; i < 4096; i += 256) A[i] = qbg[b * L + i];
    __syncthreads();
    box3_16cube(A, Bf, tid, Q);

    for (int i = tid; i < 4096; i += 256) A[i] = sbg[b * L + i];
    __syncthreads();
    box3_16cube(A, Bf, tid, Sb);

    for (int z = 0; z < 16; z++) {
        float denom = Q[z] + 2e-7f * Sb[z] + 1.728e-11f;
        invn[b * L + x * 256 + y * 16 + z] = rsqrtf(denom);
    }

    for (int i = tid; i < 4096; i += 256) A[i] = sfm[b * L + i];
    __syncthreads();
    box3_16cube(A, Bf, tid, r);
    for (int z = 0; z < 16; z++) A[x * 256 + y * 16 + z] = r[z];
    __syncthreads();
    box3_16cube(A, Bf, tid, r);
    for (int z = 0; z < 16; z++) s2fm[b * L + x * 256 + y * 16 + z] = r[z];
}

// ---------------------------------------------------------------------------
// K3: Gram matrix G[l][p] = sum_c bg[c,l]*fm[c,p], fused with the z-axis
// diagonal pass: out[l,p] = G[l,p] + G[l-1,p-1] + G[l+1,p+1]  (z-valid only).
// 64x64 tiles cover full z-range of both l and p, so the z-shift is in-tile.
// ---------------------------------------------------------------------------
__global__ __launch_bounds__(256) void k_gram_diagz(const float* __restrict__ fmb,
                                                    const float* __restrict__ bgb,
                                                    float* __restrict__ out) {
    __shared__ float As[64][64];   // bg[c][l_local]
    __shared__ float Bs[64][64];   // fm[c][p_local]
    __shared__ float Gs[64][65];
    int tid = threadIdx.x;
    int l0 = blockIdx.y * 64, p0 = blockIdx.x * 64;
    for (int i = tid; i < 64 * 64; i += 256) {
        int c = i >> 6, j = i & 63;
        As[c][j] = bgb[(size_t)c * L + l0 + j];
        Bs[c][j] = fmb[(size_t)c * L + p0 + j];
    }
    __syncthreads();
    int tx = tid & 15, ty = tid >> 4;
    float acc[4][4];
    for (int i = 0; i < 4; i++) for (int j = 0; j < 4; j++) acc[i][j] = 0.f;
    for (int c = 0; c < 64; c++) {
        float a[4], bv[4];
        #pragma unroll
        for (int i = 0; i < 4; i++) a[i] = As[c][ty * 4 + i];
        #pragma unroll
        for (int j = 0; j < 4; j++) bv[j] = Bs[c][tx * 4 + j];
        #pragma unroll
        for (int i = 0; i < 4; i++)
            #pragma unroll
            for (int j = 0; j < 4; j++) acc[i][j] += a[i] * bv[j];
    }
    __syncthreads();
    for (int i = 0; i < 4; i++)
        for (int j = 0; j < 4; j++)
            Gs[ty * 4 + i][tx * 4 + j] = acc[i][j];
    __syncthreads();
    for (int i = tid; i < 4096; i += 256) {
        int il = i >> 6, jp = i & 63;
        int l = l0 + il, p = p0 + jp;
        int lz = l & 15, pz = p & 15;
        float v = Gs[il][jp];
        if (lz > 0 && pz > 0)   v += Gs[il - 1][jp - 1];
        if (lz < 15 && pz < 15) v += Gs[il + 1][jp + 1];
        out[(size_t)l * L + p] = v;
    }
}

// ---------------------------------------------------------------------------
// K4: diagonal pass along one axis (DELTA = 16 for y, 256 for x):
//   out[l,p] = in[l,p] + in[l-D,p-D] + in[l+D,p+D]   (validity per axis coord)
// ---------------------------------------------------------------------------
template <int DELTA>
__global__ void k_diag(const float* __restrict__ in, float* __restrict__ out) {
    int idx = blockIdx.x * 1024 + threadIdx.x;
    #pragma unroll
    for (int e = 0; e < 4; e++, idx += 256) {
        int l = idx >> 12, p = idx & 4095;
        int lc = (l / DELTA) & 15, pc = (p / DELTA) & 15;
        float v = in[idx];
        if (lc > 0 && pc > 0)   v += in[idx - DELTA * 4097];
        if (lc < 15 && pc < 15) v += in[idx + DELTA * 4097];
        out[idx] = v;
    }
}

// ---------------------------------------------------------------------------
// K5: per-l row: logits[l,p] = (box3_p(C)[l,p] + 1e-7*S2fm[p]) * inv_norm[l]
// ---------------------------------------------------------------------------
__global__ void k_boxlogit(const float* __restrict__ in, float* __restrict__ out,
                           const float* __restrict__ s2fm, const float* __restrict__ invn) {
    __shared__ float A[4096];
    __shared__ float Bf[4096];
    int l = blockIdx.x;
    int tid = threadIdx.x;
    const float* row = in + (size_t)l * L;
    for (int i = tid; i < 4096; i += 256) A[i] = row[i];
    __syncthreads();
    float res[16];
    box3_16cube(A, Bf, tid, res);
    float inl = invn[l];
    int x = tid >> 4, y = tid & 15;
    float* orow = out + (size_t)l * L + x * 256 + y * 16;
    const float* s2 = s2fm + x * 256 + y * 16;
    for (int z = 0; z < 16; z++) orow[z] = (res[z] + 1e-7f * s2[z]) * inl;
}

// ---------------------------------------------------------------------------
// K6: column (over l) softmax statistics, chunked deterministic.
// ---------------------------------------------------------------------------
__global__ void k_colmax_part(const float* __restrict__ logits, float* __restrict__ pmax) {
    int p = blockIdx.x * 256 + threadIdx.x;
    int lc = blockIdx.y;
    const float* col = logits + (size_t)lc * 256 * L + p;
    float m = -1e30f;
    for (int i = 0; i < 256; i++) m = fmaxf(m, col[(size_t)i * L]);
    pmax[lc * L + p] = m;
}

__global__ void k_colmax_merge(const float* __restrict__ pmax, float* __restrict__ colmax) {
    int p = blockIdx.x * 256 + threadIdx.x;
    float m = -1e30f;
    for (int i = 0; i < 16; i++) m = fmaxf(m, pmax[i * L + p]);
    colmax[p] = m;
}

__global__ void k_colsum_part(const float* __restrict__ logits, const float* __restrict__ colmax,
                              const float* __restrict__ invn,
                              float* __restrict__ psum, float* __restrict__ psumi) {
    int p = blockIdx.x * 256 + threadIdx.x;
    int lc = blockIdx.y;
    float m = colmax[p];
    float s = 0.f, si = 0.f;
    const float* col = logits + (size_t)lc * 256 * L + p;
    for (int i = 0; i < 256; i++) {
        float e = __expf(col[(size_t)i * L] - m);
        s += e;
        si += e * invn[lc * 256 + i];
    }
    psum[lc * L + p] = s;
    psumi[lc * L + p] = si;
}

__global__ void k_colsum_merge(const float* __restrict__ psum, const float* __restrict__ psumi,
                               float* __restrict__ csi, float* __restrict__ Tarr) {
    int p = blockIdx.x * 256 + threadIdx.x;
    float s = 0.f, si = 0.f;
    for (int i = 0; i < 16; i++) { s += psum[i * L + p]; si += psumi[i * L + p]; }
    float inv = 1.f / s;
    csi[p] = inv;
    Tarr[p] = si * inv;
}

// Tbox = box3(T), one block
__global__ void k_tbox(const float* __restrict__ T, float* __restrict__ Tb) {
    __shared__ float A[4096];
    __shared__ float Bf[4096];
    int tid = threadIdx.x;
    for (int i = tid; i < 4096; i += 256) A[i] = T[i];
    __syncthreads();
    float res[16];
    box3_16cube(A, Bf, tid, res);
    int x = tid >> 4, y = tid & 15;
    for (int z = 0; z < 16; z++) Tb[x * 256 + y * 16 + z] = res[z];
}

// ---------------------------------------------------------------------------
// K7: apply softmax (a' = exp(logit-max)*csi*inv_norm) fused with z-diag pass.
// ---------------------------------------------------------------------------
__global__ void k_softmax_diagz(const float* __restrict__ in, float* __restrict__ out,
                                const float* __restrict__ colmax, const float* __restrict__ csi,
                                const float* __restrict__ invn) {
    int idx = blockIdx.x * 1024 + threadIdx.x;
    #pragma unroll
    for (int e = 0; e < 4; e++, idx += 256) {
        int l = idx >> 12, p = idx & 4095;
        int lz = l & 15, pz = p & 15;
        float v = __expf(in[idx] - colmax[p]) * csi[p] * invn[l];
        if (lz > 0 && pz > 0)
            v += __expf(in[idx - 4097] - colmax[p - 1]) * csi[p - 1] * invn[l - 1];
        if (lz < 15 && pz < 15)
            v += __expf(in[idx + 4097] - colmax[p + 1]) * csi[p + 1] * invn[l + 1];
        out[idx] = v;
    }
}

// ---------------------------------------------------------------------------
// K11: split-K matmul partials: part[mc][c][p] = sum_{m in chunk} bg[c,m]*H[m,p]
// ---------------------------------------------------------------------------
__global__ __launch_bounds__(256) void k_mm_part(const float* __restrict__ H,
                                                 const float* __restrict__ bgb,
                                                 float* __restrict__ part) {
    int tid = threadIdx.x;
    int tx = tid & 15, ty = tid >> 4;
    int p0 = blockIdx.x * 128 + tx * 8;
    int c0 = ty * 4;
    int m0 = blockIdx.y * 256;
    float acc[4][8];
    for (int i = 0; i < 4; i++) for (int j = 0; j < 8; j++) acc[i][j] = 0.f;
    for (int m = m0; m < m0 + 256; m++) {
        const float4* hr = (const float4*)(H + (size_t)m * L + p0);
        float4 ha = hr[0], hb = hr[1];
        float h[8] = {ha.x, ha.y, ha.z, ha.w, hb.x, hb.y, hb.z, hb.w};
        #pragma unroll
        for (int i = 0; i < 4; i++) {
            float bv = bgb[(size_t)(c0 + i) * L + m];
            #pragma unroll
            for (int j = 0; j < 8; j++) acc[i][j] += bv * h[j];
        }
    }
    float* pp = part + (size_t)blockIdx.y * NC * L;
    for (int i = 0; i < 4; i++)
        for (int j = 0; j < 8; j++)
            pp[(size_t)(c0 + i) * L + p0 + j] = acc[i][j];
}

// ---------------------------------------------------------------------------
// K12: reduce partials + epilogue:
//   out = (R + 1e-7*Tbox[p]) * mask/27 + fm*(1-mask)
// ---------------------------------------------------------------------------
__global__ void k_epilogue(const float* __restrict__ part, const float* __restrict__ Tbox,
                           const float* __restrict__ mask_b, const float* __restrict__ fm_b,
                           float* __restrict__ out_b) {
    int idx = blockIdx.x * 256 + threadIdx.x;   // over NC*L
    int p = idx & 4095;
    float s = 0.f;
    for (int i = 0; i < 16; i++) s += part[(size_t)i * NC * L + idx];
    float m = mask_b[p];
    float r = (s + 1e-7f * Tbox[p]) * m * (1.f / 27.f);
    out_b[idx] = r + fm_b[idx] * (1.f - m);
}

// ---------------------------------------------------------------------------
extern "C" void kernel_launch(void* const* d_in, const int* in_sizes, int n_in,
                              void* d_out, int out_size, void* d_ws, size_t ws_size,
                              hipStream_t stream) {
    const float* fm = (const float*)d_in[0];
    const float* mask = (const float*)d_in[1];
    float* out = (float*)d_out;
    float* ws = (float*)d_ws;

    const size_t LL = (size_t)L * L;           // 16,777,216
    float* buf0 = ws;
    float* buf1 = ws + LL;
    float* bg   = ws + 2 * LL;                 // BZ*NC*L = 1,048,576
    float* sfm  = bg + (size_t)BZ * NC * L;
    float* sbg  = sfm + (size_t)BZ * L;
    float* qbg  = sbg + (size_t)BZ * L;
    float* invn = qbg + (size_t)BZ * L;
    float* s2fm = invn + (size_t)BZ * L;
    float* colmax = s2fm + (size_t)BZ * L;
    float* csi    = colmax + L;
    float* Tarr   = csi + L;
    float* Tbox   = Tarr + L;
    float* pmax   = Tbox + L;                  // 16*L
    float* psum   = pmax + 16 * L;
    float* psumi  = psum + 16 * L;

    k_prep<<<dim3(16, BZ), 256, 0, stream>>>(fm, mask, bg, sfm, sbg, qbg);
    k_stats<<<BZ, 256, 0, stream>>>(sfm, sbg, qbg, invn, s2fm);

    for (int b = 0; b < BZ; b++) {
        const float* fmb = fm + (size_t)b * NC * L;
        const float* bgb = bg + (size_t)b * NC * L;
        const float* invnb = invn + (size_t)b * L;
        const float* s2b = s2fm + (size_t)b * L;
        const float* maskb = mask + (size_t)b * L;
        float* outb = out + (size_t)b * NC * L;

        // G (with z-diag fused) -> buf0
        k_gram_diagz<<<dim3(64, 64), 256, 0, stream>>>(fmb, bgb, buf0);
        // y, x diag passes -> C in buf0
        k_diag<16><<<16384, 256, 0, stream>>>(buf0, buf1);
        k_diag<256><<<16384, 256, 0, stream>>>(buf1, buf0);
        // box3 over p + logits -> buf1
        k_boxlogit<<<4096, 256, 0, stream>>>(buf0, buf1, s2b, invnb);
        // softmax stats
        k_colmax_part<<<dim3(16, 16), 256, 0, stream>>>(buf1, pmax);
        k_colmax_merge<<<16, 256, 0, stream>>>(pmax, colmax);
        k_colsum_part<<<dim3(16, 16), 256, 0, stream>>>(buf1, colmax, invnb, psum, psumi);
        k_colsum_merge<<<16, 256, 0, stream>>>(psum, psumi, csi, Tarr);
        k_tbox<<<1, 256, 0, stream>>>(Tarr, Tbox);
        // H = diag3(a') : softmax-apply fused with z pass, then y, x
        k_softmax_diagz<<<16384, 256, 0, stream>>>(buf1, buf0, colmax, csi, invnb);
        k_diag<16><<<16384, 256, 0, stream>>>(buf0, buf1);
        k_diag<256><<<16384, 256, 0, stream>>>(buf1, buf0);   // H in buf0
        // R = bg @ H (split-K partials into buf1), then epilogue
        k_mm_part<<<dim3(32, 16), 256, 0, stream>>>(buf0, bgb, buf1);
        k_epilogue<<<1024, 256, 0, stream>>>(buf1, Tbox, maskb, fmb, outb);
    }
}

// Round 2
// 1081.420 us; speedup vs baseline: 1.6991x; 1.6991x over previous
//
#include <hip/hip_runtime.h>
#include <hip/hip_bf16.h>
#include <math.h>

#define L 4096      // 16^3
#define NC 64
#define BZ 4
#define PS 17       // padded z-stride (bank-conflict-free)
#define PXD 272     // 16*PS

// ---------------------------------------------------------------------------
// 3x3x3 ones box filter (zero padded) on a 16^3 cube in PADDED LDS.
// A holds input at [x*PXD + y*PS + z]; clobbered. B is scratch.
// Thread (x=tid>>4, y=tid&15) returns its z-line in out[16].
// Caller must __syncthreads() after filling A if fill was cross-thread.
// ---------------------------------------------------------------------------
__device__ void box3_pad(float* A, float* B, int tid, float out[16]) {
    int x = tid >> 4, y = tid & 15;
    int base = x * PXD + y * PS;
    float t[16];
    {
        float line[16];
        #pragma unroll
        for (int z = 0; z < 16; z++) line[z] = A[base + z];
        #pragma unroll
        for (int z = 0; z < 16; z++) {
            float s = line[z];
            if (z > 0)  s += line[z - 1];
            if (z < 15) s += line[z + 1];
            t[z] = s;
        }
    }
    #pragma unroll
    for (int z = 0; z < 16; z++) B[base + z] = t[z];
    __syncthreads();
    #pragma unroll
    for (int z = 0; z < 16; z++) {
        float s = B[base + z];
        if (y > 0)  s += B[base - PS + z];
        if (y < 15) s += B[base + PS + z];
        t[z] = s;
    }
    __syncthreads();
    #pragma unroll
    for (int z = 0; z < 16; z++) A[base + z] = t[z];
    __syncthreads();
    #pragma unroll
    for (int z = 0; z < 16; z++) {
        float s = A[base + z];
        if (x > 0)  s += A[base - PXD + z];
        if (x < 15) s += A[base + PXD + z];
        out[z] = s;
    }
    __syncthreads();
}

__device__ inline void fill_pad(float* A, const float* __restrict__ g, int tid) {
    for (int i = tid; i < 4096; i += 256)
        A[(i >> 8) * PXD + ((i >> 4) & 15) * PS + (i & 15)] = g[i];
    __syncthreads();
}

// ---------------------------------------------------------------------------
// K1: bg = fm*(1-mask); channel sums sfm, sbg, qbg.
// ---------------------------------------------------------------------------
__global__ void k_prep(const float* __restrict__ fm, const float* __restrict__ mask,
                       float* __restrict__ bg, float* __restrict__ sfm,
                       float* __restrict__ sbg, float* __restrict__ qbg) {
    int b = blockIdx.y;
    int p = blockIdx.x * 256 + threadIdx.x;
    float m = mask[b * L + p];
    float w = 1.f - m;
    float s_f = 0.f, s_b = 0.f, q_b = 0.f;
    const float* fmb = fm + (size_t)b * NC * L + p;
    float* bgb = bg + (size_t)b * NC * L + p;
    for (int c = 0; c < NC; c++) {
        float f = fmb[(size_t)c * L];
        float g = f * w;
        bgb[(size_t)c * L] = g;
        s_f += f; s_b += g; q_b += g * g;
    }
    sfm[b * L + p] = s_f;
    sbg[b * L + p] = s_b;
    qbg[b * L + p] = q_b;
}

// ---------------------------------------------------------------------------
// K2: inv_norm = rsqrt(box3(qbg) + 2e-7*box3(sbg) + 1728e-14); s2fm = box3^2(sfm)
// ---------------------------------------------------------------------------
__global__ void k_stats(const float* __restrict__ sfm, const float* __restrict__ sbg,
                        const float* __restrict__ qbg,
                        float* __restrict__ invn, float* __restrict__ s2fm) {
    __shared__ float A[16 * PXD];
    __shared__ float Bf[16 * PXD];
    int b = blockIdx.x;
    int tid = threadIdx.x;
    int x = tid >> 4, y = tid & 15;
    float Q[16], Sb[16], r[16];

    fill_pad(A, qbg + b * L, tid);
    box3_pad(A, Bf, tid, Q);

    fill_pad(A, sbg + b * L, tid);
    box3_pad(A, Bf, tid, Sb);

    for (int z = 0; z < 16; z++) {
        float denom = Q[z] + 2e-7f * Sb[z] + 1.728e-11f;
        invn[b * L + x * 256 + y * 16 + z] = rsqrtf(denom);
    }

    fill_pad(A, sfm + b * L, tid);
    box3_pad(A, Bf, tid, r);
    int base = x * PXD + y * PS;
    #pragma unroll
    for (int z = 0; z < 16; z++) A[base + z] = r[z];
    __syncthreads();
    box3_pad(A, Bf, tid, r);
    for (int z = 0; z < 16; z++) s2fm[b * L + x * 256 + y * 16 + z] = r[z];
}

// ---------------------------------------------------------------------------
// K3: Gram G[l][p] = sum_c bg[c,l]*fm[c,p] fused with z-axis diagonal pass.
// ---------------------------------------------------------------------------
__global__ __launch_bounds__(256) void k_gram_diagz(const float* __restrict__ fmb,
                                                    const float* __restrict__ bgb,
                                                    float* __restrict__ out) {
    __shared__ float As[64][64];
    __shared__ float Bs[64][64];
    __shared__ float Gs[64][65];
    int tid = threadIdx.x;
    int l0 = blockIdx.y * 64, p0 = blockIdx.x * 64;
    for (int i = tid; i < 64 * 64; i += 256) {
        int c = i >> 6, j = i & 63;
        As[c][j] = bgb[(size_t)c * L + l0 + j];
        Bs[c][j] = fmb[(size_t)c * L + p0 + j];
    }
    __syncthreads();
    int tx = tid & 15, ty = tid >> 4;
    float acc[4][4];
    for (int i = 0; i < 4; i++) for (int j = 0; j < 4; j++) acc[i][j] = 0.f;
    for (int c = 0; c < 64; c++) {
        float a[4], bv[4];
        #pragma unroll
        for (int i = 0; i < 4; i++) a[i] = As[c][ty * 4 + i];
        #pragma unroll
        for (int j = 0; j < 4; j++) bv[j] = Bs[c][tx * 4 + j];
        #pragma unroll
        for (int i = 0; i < 4; i++)
            #pragma unroll
            for (int j = 0; j < 4; j++) acc[i][j] += a[i] * bv[j];
    }
    __syncthreads();
    for (int i = 0; i < 4; i++)
        for (int j = 0; j < 4; j++)
            Gs[ty * 4 + i][tx * 4 + j] = acc[i][j];
    __syncthreads();
    for (int i = tid; i < 4096; i += 256) {
        int il = i >> 6, jp = i & 63;
        int l = l0 + il, p = p0 + jp;
        int lz = l & 15, pz = p & 15;
        float v = Gs[il][jp];
        if (lz > 0 && pz > 0)   v += Gs[il - 1][jp - 1];
        if (lz < 15 && pz < 15) v += Gs[il + 1][jp + 1];
        out[(size_t)l * L + p] = v;
    }
}

// ---------------------------------------------------------------------------
// K4 (fused): per l-row: apply diag-y + diag-x (9 shifted-row reads, L2-local:
// all row offsets are multiples of 8 -> same XCD), then box3 over p in padded
// LDS, then logits = (. + 1e-7*s2fm)*invn[l]. One read + one write pass.
// ---------------------------------------------------------------------------
__global__ __launch_bounds__(256) void k_rowlogit(const float* __restrict__ Cz,
                                                  float* __restrict__ out,
                                                  const float* __restrict__ s2fm,
                                                  const float* __restrict__ invn) {
    __shared__ float A[16 * PXD];
    __shared__ float Bf[16 * PXD];
    int l = blockIdx.x;
    int lx = l >> 8, ly = (l >> 4) & 15;
    int tid = threadIdx.x;
    int px = tid >> 4, py = tid & 15;
    float c[16];
    #pragma unroll
    for (int z = 0; z < 16; z++) c[z] = 0.f;

    #pragma unroll
    for (int dx = -1; dx <= 1; dx++) {
        #pragma unroll
        for (int dy = -1; dy <= 1; dy++) {
            if (lx + dx < 0 || lx + dx > 15 || px + dx < 0 || px + dx > 15) continue;
            if (ly + dy < 0 || ly + dy > 15 || py + dy < 0 || py + dy > 15) continue;
            const float* src = Cz + (size_t)(l + dy * 16 + dx * 256) * L
                               + (px + dx) * 256 + (py + dy) * 16;
            const float4* s4 = (const float4*)src;
            float4 v0 = s4[0], v1 = s4[1], v2 = s4[2], v3 = s4[3];
            c[0] += v0.x; c[1] += v0.y; c[2] += v0.z; c[3] += v0.w;
            c[4] += v1.x; c[5] += v1.y; c[6] += v1.z; c[7] += v1.w;
            c[8] += v2.x; c[9] += v2.y; c[10] += v2.z; c[11] += v2.w;
            c[12] += v3.x; c[13] += v3.y; c[14] += v3.z; c[15] += v3.w;
        }
    }
    int base = px * PXD + py * PS;
    #pragma unroll
    for (int z = 0; z < 16; z++) A[base + z] = c[z];   // own line; helper syncs
    float res[16];
    box3_pad(A, Bf, tid, res);
    float inl = invn[l];
    float* orow = out + (size_t)l * L + px * 256 + py * 16;
    const float* s2 = s2fm + px * 256 + py * 16;
    for (int z = 0; z < 16; z++) orow[z] = (res[z] + 1e-7f * s2[z]) * inl;
}

// ---------------------------------------------------------------------------
// K5: online (flash-style) column softmax stats: one read of logits.
// ---------------------------------------------------------------------------
__global__ void k_colstat_part(const float* __restrict__ logits, const float* __restrict__ invn,
                               float* __restrict__ pm, float* __restrict__ ps,
                               float* __restrict__ psi) {
    int p = blockIdx.x * 256 + threadIdx.x;
    int lc = blockIdx.y;
    const float* col = logits + (size_t)lc * 256 * L + p;
    const float* inv = invn + lc * 256;
    float m = -1e30f, s = 0.f, si = 0.f;
    for (int i = 0; i < 256; i++) {
        float x = col[(size_t)i * L];
        float nm = fmaxf(m, x);
        float cc = __expf(m - nm);
        float e = __expf(x - nm);
        s = s * cc + e;
        si = si * cc + e * inv[i];
        m = nm;
    }
    pm[lc * L + p] = m;
    ps[lc * L + p] = s;
    psi[lc * L + p] = si;
}

__global__ void k_colstat_merge(const float* __restrict__ pm, const float* __restrict__ ps,
                                const float* __restrict__ psi,
                                float* __restrict__ colmax, float* __restrict__ csi,
                                float* __restrict__ Tarr) {
    int p = blockIdx.x * 256 + threadIdx.x;
    float m = -1e30f;
    for (int i = 0; i < 16; i++) m = fmaxf(m, pm[i * L + p]);
    float s = 0.f, si = 0.f;
    for (int i = 0; i < 16; i++) {
        float cc = __expf(pm[i * L + p] - m);
        s += ps[i * L + p] * cc;
        si += psi[i * L + p] * cc;
    }
    float inv = 1.f / s;
    colmax[p] = m;
    csi[p] = inv;
    Tarr[p] = si * inv;
}

// Tbox = box3(T), one block
__global__ void k_tbox(const float* __restrict__ T, float* __restrict__ Tb) {
    __shared__ float A[16 * PXD];
    __shared__ float Bf[16 * PXD];
    int tid = threadIdx.x;
    fill_pad(A, T, tid);
    float res[16];
    box3_pad(A, Bf, tid, res);
    int x = tid >> 4, y = tid & 15;
    for (int z = 0; z < 16; z++) Tb[x * 256 + y * 16 + z] = res[z];
}

// ---------------------------------------------------------------------------
// K6: softmax-apply (a' = exp(logit-max)*csi*invn) fused with z-diag pass.
// ---------------------------------------------------------------------------
__global__ void k_sm_diagz(const float* __restrict__ in, float* __restrict__ out,
                           const float* __restrict__ colmax, const float* __restrict__ csi,
                           const float* __restrict__ invn) {
    int idx = blockIdx.x * 1024 + threadIdx.x;
    #pragma unroll
    for (int e = 0; e < 4; e++, idx += 256) {
        int l = idx >> 12, p = idx & 4095;
        int lz = l & 15, pz = p & 15;
        float v = __expf(in[idx] - colmax[p]) * csi[p] * invn[l];
        if (lz > 0 && pz > 0)
            v += __expf(in[idx - 4097] - colmax[p - 1]) * csi[p - 1] * invn[l - 1];
        if (lz < 15 && pz < 15)
            v += __expf(in[idx + 4097] - colmax[p + 1]) * csi[p + 1] * invn[l + 1];
        out[idx] = v;
    }
}

// ---------------------------------------------------------------------------
// K7: fused y+x diagonal pass: out[l,p] = sum_{dy,dx} valid * in[l+D, p+D],
// D = dy*16+dx*256. 9 coalesced streams; re-reads served by L2/LLC.
// ---------------------------------------------------------------------------
__global__ void k_diag2(const float* __restrict__ in, float* __restrict__ out) {
    int i4 = (blockIdx.x * 256 + threadIdx.x) * 4;
    int l = i4 >> 12, p = i4 & 4095;
    int lx = l >> 8, ly = (l >> 4) & 15;
    int px = p >> 8, py = (p >> 4) & 15;
    float4 acc = *(const float4*)(in + i4);   // (0,0) always valid
    #pragma unroll
    for (int dx = -1; dx <= 1; dx++) {
        #pragma unroll
        for (int dy = -1; dy <= 1; dy++) {
            if (dx == 0 && dy == 0) continue;
            if (lx + dx < 0 || lx + dx > 15 || px + dx < 0 || px + dx > 15) continue;
            if (ly + dy < 0 || ly + dy > 15 || py + dy < 0 || py + dy > 15) continue;
            const int doff = (dy * 16 + dx * 256) * 4097;
            float4 v = *(const float4*)(in + i4 + doff);
            acc.x += v.x; acc.y += v.y; acc.z += v.z; acc.w += v.w;
        }
    }
    *(float4*)(out + i4) = acc;
}

// ---------------------------------------------------------------------------
// K8: split-K matmul partials: part[mc][c][p] = sum_{m in chunk} bg[c,m]*H[m,p]
// ---------------------------------------------------------------------------
__global__ __launch_bounds__(256) void k_mm_part(const float* __restrict__ H,
                                                 const float* __restrict__ bgb,
                                                 float* __restrict__ part) {
    int tid = threadIdx.x;
    int tx = tid & 15, ty = tid >> 4;
    int p0 = blockIdx.x * 128 + tx * 8;
    int c0 = ty * 4;
    int m0 = blockIdx.y * 256;
    float acc[4][8];
    for (int i = 0; i < 4; i++) for (int j = 0; j < 8; j++) acc[i][j] = 0.f;
    for (int m = m0; m < m0 + 256; m++) {
        const float4* hr = (const float4*)(H + (size_t)m * L + p0);
        float4 ha = hr[0], hb = hr[1];
        float h[8] = {ha.x, ha.y, ha.z, ha.w, hb.x, hb.y, hb.z, hb.w};
        #pragma unroll
        for (int i = 0; i < 4; i++) {
            float bv = bgb[(size_t)(c0 + i) * L + m];
            #pragma unroll
            for (int j = 0; j < 8; j++) acc[i][j] += bv * h[j];
        }
    }
    float* pp = part + (size_t)blockIdx.y * NC * L;
    for (int i = 0; i < 4; i++)
        for (int j = 0; j < 8; j++)
            pp[(size_t)(c0 + i) * L + p0 + j] = acc[i][j];
}

// ---------------------------------------------------------------------------
// K9: reduce partials + epilogue.
// ---------------------------------------------------------------------------
__global__ void k_epilogue(const float* __restrict__ part, const float* __restrict__ Tbox,
                           const float* __restrict__ mask_b, const float* __restrict__ fm_b,
                           float* __restrict__ out_b) {
    int idx = blockIdx.x * 256 + threadIdx.x;
    int p = idx & 4095;
    float s = 0.f;
    for (int i = 0; i < 16; i++) s += part[(size_t)i * NC * L + idx];
    float m = mask_b[p];
    float r = (s + 1e-7f * Tbox[p]) * m * (1.f / 27.f);
    out_b[idx] = r + fm_b[idx] * (1.f - m);
}

// ---------------------------------------------------------------------------
extern "C" void kernel_launch(void* const* d_in, const int* in_sizes, int n_in,
                              void* d_out, int out_size, void* d_ws, size_t ws_size,
                              hipStream_t stream) {
    const float* fm = (const float*)d_in[0];
    const float* mask = (const float*)d_in[1];
    float* out = (float*)d_out;
    float* ws = (float*)d_ws;

    const size_t LL = (size_t)L * L;
    float* buf0 = ws;
    float* buf1 = ws + LL;
    float* bg   = ws + 2 * LL;
    float* sfm  = bg + (size_t)BZ * NC * L;
    float* sbg  = sfm + (size_t)BZ * L;
    float* qbg  = sbg + (size_t)BZ * L;
    float* invn = qbg + (size_t)BZ * L;
    float* s2fm = invn + (size_t)BZ * L;
    float* colmax = s2fm + (size_t)BZ * L;
    float* csi    = colmax + L;
    float* Tarr   = csi + L;
    float* Tbox   = Tarr + L;
    float* pmax   = Tbox + L;
    float* psum   = pmax + 16 * L;
    float* psumi  = psum + 16 * L;

    k_prep<<<dim3(16, BZ), 256, 0, stream>>>(fm, mask, bg, sfm, sbg, qbg);
    k_stats<<<BZ, 256, 0, stream>>>(sfm, sbg, qbg, invn, s2fm);

    for (int b = 0; b < BZ; b++) {
        const float* fmb = fm + (size_t)b * NC * L;
        const float* bgb = bg + (size_t)b * NC * L;
        const float* invnb = invn + (size_t)b * L;
        const float* s2b = s2fm + (size_t)b * L;
        const float* maskb = mask + (size_t)b * L;
        float* outb = out + (size_t)b * NC * L;

        k_gram_diagz<<<dim3(64, 64), 256, 0, stream>>>(fmb, bgb, buf0);
        k_rowlogit<<<4096, 256, 0, stream>>>(buf0, buf1, s2b, invnb);
        k_colstat_part<<<dim3(16, 16), 256, 0, stream>>>(buf1, invnb, pmax, psum, psumi);
        k_colstat_merge<<<16, 256, 0, stream>>>(pmax, psum, psumi, colmax, csi, Tarr);
        k_tbox<<<1, 256, 0, stream>>>(Tarr, Tbox);
        k_sm_diagz<<<16384, 256, 0, stream>>>(buf1, buf0, colmax, csi, invnb);
        k_diag2<<<16384, 256, 0, stream>>>(buf0, buf1);
        k_mm_part<<<dim3(32, 16), 256, 0, stream>>>(buf1, bgb, buf0);
        k_epilogue<<<1024, 256, 0, stream>>>(buf0, Tbox, maskb, fmb, outb);
    }
}

// Round 3
// 977.522 us; speedup vs baseline: 1.8796x; 1.1063x over previous
//
#include <hip/hip_runtime.h>
#include <hip/hip_bf16.h>
#include <math.h>

#define L 4096      // 16^3
#define NC 64
#define BZ 4
#define PS 17       // padded z-stride (bank-conflict-free)
#define PXD 272     // 16*PS

typedef __attribute__((ext_vector_type(8))) short bf16x8;
typedef __attribute__((ext_vector_type(4))) float f32x4;

__device__ inline unsigned short f2bf(float f) {
    unsigned int u = __float_as_uint(f);
    unsigned int r = (u + 0x7fffu + ((u >> 16) & 1u)) >> 16;   // RNE
    return (unsigned short)r;
}

// ---------------------------------------------------------------------------
// box3 on padded 16^3 LDS cube (thread (x=tid>>4,y=tid&15) -> z-line out[16])
// ---------------------------------------------------------------------------
__device__ void box3_pad(float* A, float* B, int tid, float out[16]) {
    int x = tid >> 4, y = tid & 15;
    int base = x * PXD + y * PS;
    float t[16];
    {
        float line[16];
        #pragma unroll
        for (int z = 0; z < 16; z++) line[z] = A[base + z];
        #pragma unroll
        for (int z = 0; z < 16; z++) {
            float s = line[z];
            if (z > 0)  s += line[z - 1];
            if (z < 15) s += line[z + 1];
            t[z] = s;
        }
    }
    #pragma unroll
    for (int z = 0; z < 16; z++) B[base + z] = t[z];
    __syncthreads();
    #pragma unroll
    for (int z = 0; z < 16; z++) {
        float s = B[base + z];
        if (y > 0)  s += B[base - PS + z];
        if (y < 15) s += B[base + PS + z];
        t[z] = s;
    }
    __syncthreads();
    #pragma unroll
    for (int z = 0; z < 16; z++) A[base + z] = t[z];
    __syncthreads();
    #pragma unroll
    for (int z = 0; z < 16; z++) {
        float s = A[base + z];
        if (x > 0)  s += A[base - PXD + z];
        if (x < 15) s += A[base + PXD + z];
        out[z] = s;
    }
    __syncthreads();
}

__device__ inline void fill_pad(float* A, const float* __restrict__ g, int tid) {
    for (int i = tid; i < 4096; i += 256)
        A[(i >> 8) * PXD + ((i >> 4) & 15) * PS + (i & 15)] = g[i];
    __syncthreads();
}

// ---------------------------------------------------------------------------
// K1: bg=fm*(1-mask); bf16 copies bgT[l][c], fmT[p][c], bgh[c][p]; f32 sums.
// ---------------------------------------------------------------------------
__global__ void k_prep(const float* __restrict__ fm, const float* __restrict__ mask,
                       unsigned short* __restrict__ bgT, unsigned short* __restrict__ fmT,
                       unsigned short* __restrict__ bgh,
                       float* __restrict__ sfm, float* __restrict__ sbg,
                       float* __restrict__ qbg) {
    int b = blockIdx.y;
    int p = blockIdx.x * 256 + threadIdx.x;
    float m = mask[b * L + p];
    float w = 1.f - m;
    float s_f = 0.f, s_b = 0.f, q_b = 0.f;
    const float* fmb = fm + (size_t)b * NC * L + p;
    unsigned short* bghb = bgh + (size_t)b * NC * L + p;
    unsigned short tA[NC], tB[NC];
    #pragma unroll
    for (int c = 0; c < NC; c++) {
        float f = fmb[(size_t)c * L];
        float g = f * w;
        s_f += f; s_b += g; q_b += g * g;
        unsigned short gb = f2bf(g);
        tA[c] = gb;
        tB[c] = f2bf(f);
        bghb[(size_t)c * L] = gb;
    }
    unsigned short* bgTb = bgT + (size_t)b * L * NC + (size_t)p * NC;
    unsigned short* fmTb = fmT + (size_t)b * L * NC + (size_t)p * NC;
    #pragma unroll
    for (int i = 0; i < 8; i++) {
        ((uint4*)bgTb)[i] = ((const uint4*)tA)[i];
        ((uint4*)fmTb)[i] = ((const uint4*)tB)[i];
    }
    sfm[b * L + p] = s_f;
    sbg[b * L + p] = s_b;
    qbg[b * L + p] = q_b;
}

// ---------------------------------------------------------------------------
// K2: invn = rsqrt(box3(qbg)+2e-7*box3(sbg)+1728e-14); s2fm = box3(box3(sfm))
// ---------------------------------------------------------------------------
__global__ void k_stats(const float* __restrict__ sfm, const float* __restrict__ sbg,
                        const float* __restrict__ qbg,
                        float* __restrict__ invn, float* __restrict__ s2fm) {
    __shared__ float A[16 * PXD];
    __shared__ float Bf[16 * PXD];
    int b = blockIdx.x;
    int tid = threadIdx.x;
    int x = tid >> 4, y = tid & 15;
    float Q[16], Sb[16], r[16];

    fill_pad(A, qbg + b * L, tid);
    box3_pad(A, Bf, tid, Q);
    fill_pad(A, sbg + b * L, tid);
    box3_pad(A, Bf, tid, Sb);
    for (int z = 0; z < 16; z++) {
        float denom = Q[z] + 2e-7f * Sb[z] + 1.728e-11f;
        invn[b * L + x * 256 + y * 16 + z] = rsqrtf(denom);
    }
    fill_pad(A, sfm + b * L, tid);
    box3_pad(A, Bf, tid, r);
    int base = x * PXD + y * PS;
    #pragma unroll
    for (int z = 0; z < 16; z++) A[base + z] = r[z];
    __syncthreads();
    box3_pad(A, Bf, tid, r);
    for (int z = 0; z < 16; z++) s2fm[b * L + x * 256 + y * 16 + z] = r[z];
}

// ---------------------------------------------------------------------------
// K3: MFMA Gram G[l][p] = sum_c bg[c,l]*fm[c,p], fused z-diag pass.
// A: rows=l, k=c from bgT[l][c]; B: cols=p, k=c from fmT[p][c].
// ---------------------------------------------------------------------------
__global__ __launch_bounds__(256) void k_gram_mfma(const unsigned short* __restrict__ bgT,
                                                   const unsigned short* __restrict__ fmT,
                                                   float* __restrict__ out) {
    __shared__ float Gs[64][65];
    int tid = threadIdx.x;
    int l0 = blockIdx.y * 64, p0 = blockIdx.x * 64;
    int w = tid >> 6, lane = tid & 63;
    int rr = lane & 15, kg = lane >> 4;

    bf16x8 a0 = *(const bf16x8*)&bgT[(size_t)(l0 + w * 16 + rr) * NC + kg * 8];
    bf16x8 a1 = *(const bf16x8*)&bgT[(size_t)(l0 + w * 16 + rr) * NC + 32 + kg * 8];
    f32x4 acc[4];
    #pragma unroll
    for (int pt = 0; pt < 4; pt++) {
        bf16x8 b0 = *(const bf16x8*)&fmT[(size_t)(p0 + pt * 16 + rr) * NC + kg * 8];
        bf16x8 b1 = *(const bf16x8*)&fmT[(size_t)(p0 + pt * 16 + rr) * NC + 32 + kg * 8];
        f32x4 z; z[0] = 0.f; z[1] = 0.f; z[2] = 0.f; z[3] = 0.f;
        z = __builtin_amdgcn_mfma_f32_16x16x32_bf16(a0, b0, z, 0, 0, 0);
        z = __builtin_amdgcn_mfma_f32_16x16x32_bf16(a1, b1, z, 0, 0, 0);
        acc[pt] = z;
    }
    #pragma unroll
    for (int pt = 0; pt < 4; pt++)
        #pragma unroll
        for (int r = 0; r < 4; r++)
            Gs[w * 16 + kg * 4 + r][pt * 16 + rr] = acc[pt][r];
    __syncthreads();
    for (int i = tid; i < 4096; i += 256) {
        int il = i >> 6, jp = i & 63;
        int l = l0 + il, p = p0 + jp;
        int lz = l & 15, pz = p & 15;
        float v = Gs[il][jp];
        if (lz > 0 && pz > 0)   v += Gs[il - 1][jp - 1];
        if (lz < 15 && pz < 15) v += Gs[il + 1][jp + 1];
        out[(size_t)l * L + p] = v;
    }
}

// ---------------------------------------------------------------------------
// K4: per l-row: diag-y + diag-x (9 shifted-row reads), box3 over p, logits.
// ---------------------------------------------------------------------------
__global__ __launch_bounds__(256) void k_rowlogit(const float* __restrict__ Cz,
                                                  float* __restrict__ out,
                                                  const float* __restrict__ s2fm,
                                                  const float* __restrict__ invn) {
    __shared__ float A[16 * PXD];
    __shared__ float Bf[16 * PXD];
    int l = blockIdx.x;
    int lx = l >> 8, ly = (l >> 4) & 15;
    int tid = threadIdx.x;
    int px = tid >> 4, py = tid & 15;
    float c[16];
    #pragma unroll
    for (int z = 0; z < 16; z++) c[z] = 0.f;

    #pragma unroll
    for (int dx = -1; dx <= 1; dx++) {
        #pragma unroll
        for (int dy = -1; dy <= 1; dy++) {
            if (lx + dx < 0 || lx + dx > 15 || px + dx < 0 || px + dx > 15) continue;
            if (ly + dy < 0 || ly + dy > 15 || py + dy < 0 || py + dy > 15) continue;
            const float* src = Cz + (size_t)(l + dy * 16 + dx * 256) * L
                               + (px + dx) * 256 + (py + dy) * 16;
            const float4* s4 = (const float4*)src;
            float4 v0 = s4[0], v1 = s4[1], v2 = s4[2], v3 = s4[3];
            c[0] += v0.x; c[1] += v0.y; c[2] += v0.z; c[3] += v0.w;
            c[4] += v1.x; c[5] += v1.y; c[6] += v1.z; c[7] += v1.w;
            c[8] += v2.x; c[9] += v2.y; c[10] += v2.z; c[11] += v2.w;
            c[12] += v3.x; c[13] += v3.y; c[14] += v3.z; c[15] += v3.w;
        }
    }
    int base = px * PXD + py * PS;
    #pragma unroll
    for (int z = 0; z < 16; z++) A[base + z] = c[z];
    float res[16];
    box3_pad(A, Bf, tid, res);
    float inl = invn[l];
    float* orow = out + (size_t)l * L + px * 256 + py * 16;
    const float* s2 = s2fm + px * 256 + py * 16;
    for (int z = 0; z < 16; z++) orow[z] = (res[z] + 1e-7f * s2[z]) * inl;
}

// ---------------------------------------------------------------------------
// K5: column softmax stats: 64 l-chunks, 4 p per thread (float4, 4 ILP chains)
// ---------------------------------------------------------------------------
__global__ void k_colstat_part(const float* __restrict__ logits, const float* __restrict__ invn,
                               float* __restrict__ pm, float* __restrict__ ps,
                               float* __restrict__ psi) {
    int p4 = blockIdx.x * 1024 + threadIdx.x * 4;
    int lc = blockIdx.y;
    float m0 = -1e30f, m1 = -1e30f, m2 = -1e30f, m3 = -1e30f;
    float s0 = 0.f, s1 = 0.f, s2 = 0.f, s3 = 0.f;
    float i0 = 0.f, i1 = 0.f, i2 = 0.f, i3 = 0.f;
    const float* base = logits + (size_t)lc * 64 * L + p4;
    const float* inv = invn + lc * 64;
    for (int i = 0; i < 64; i++) {
        float4 x = *(const float4*)(base + (size_t)i * L);
        float iv = inv[i];
        float nm, cc, e;
        nm = fmaxf(m0, x.x); cc = __expf(m0 - nm); e = __expf(x.x - nm);
        s0 = s0 * cc + e; i0 = i0 * cc + e * iv; m0 = nm;
        nm = fmaxf(m1, x.y); cc = __expf(m1 - nm); e = __expf(x.y - nm);
        s1 = s1 * cc + e; i1 = i1 * cc + e * iv; m1 = nm;
        nm = fmaxf(m2, x.z); cc = __expf(m2 - nm); e = __expf(x.z - nm);
        s2 = s2 * cc + e; i2 = i2 * cc + e * iv; m2 = nm;
        nm = fmaxf(m3, x.w); cc = __expf(m3 - nm); e = __expf(x.w - nm);
        s3 = s3 * cc + e; i3 = i3 * cc + e * iv; m3 = nm;
    }
    float4* pmv = (float4*)(pm + (size_t)lc * L + p4);
    float4* psv = (float4*)(ps + (size_t)lc * L + p4);
    float4* piv = (float4*)(psi + (size_t)lc * L + p4);
    *pmv = make_float4(m0, m1, m2, m3);
    *psv = make_float4(s0, s1, s2, s3);
    *piv = make_float4(i0, i1, i2, i3);
}

__global__ void k_colstat_merge(const float* __restrict__ pm, const float* __restrict__ ps,
                                const float* __restrict__ psi,
                                float* __restrict__ colmax, float* __restrict__ csi,
                                float* __restrict__ Tarr) {
    int p = blockIdx.x * 256 + threadIdx.x;
    float m = -1e30f;
    for (int i = 0; i < 64; i++) m = fmaxf(m, pm[(size_t)i * L + p]);
    float s = 0.f, si = 0.f;
    for (int i = 0; i < 64; i++) {
        float cc = __expf(pm[(size_t)i * L + p] - m);
        s += ps[(size_t)i * L + p] * cc;
        si += psi[(size_t)i * L + p] * cc;
    }
    float inv = 1.f / s;
    colmax[p] = m;
    csi[p] = inv;
    Tarr[p] = si * inv;
}

__global__ void k_tbox(const float* __restrict__ T, float* __restrict__ Tb) {
    __shared__ float A[16 * PXD];
    __shared__ float Bf[16 * PXD];
    int tid = threadIdx.x;
    fill_pad(A, T, tid);
    float res[16];
    box3_pad(A, Bf, tid, res);
    int x = tid >> 4, y = tid & 15;
    for (int z = 0; z < 16; z++) Tb[x * 256 + y * 16 + z] = res[z];
}

// ---------------------------------------------------------------------------
// K6: softmax-apply fused with z-diag pass (a'z, f32).
// ---------------------------------------------------------------------------
__global__ void k_sm_diagz(const float* __restrict__ in, float* __restrict__ out,
                           const float* __restrict__ colmax, const float* __restrict__ csi,
                           const float* __restrict__ invn) {
    int idx = blockIdx.x * 1024 + threadIdx.x;
    #pragma unroll
    for (int e = 0; e < 4; e++, idx += 256) {
        int l = idx >> 12, p = idx & 4095;
        int lz = l & 15, pz = p & 15;
        float v = __expf(in[idx] - colmax[p]) * csi[p] * invn[l];
        if (lz > 0 && pz > 0)
            v += __expf(in[idx - 4097] - colmax[p - 1]) * csi[p - 1] * invn[l - 1];
        if (lz < 15 && pz < 15)
            v += __expf(in[idx + 4097] - colmax[p + 1]) * csi[p + 1] * invn[l + 1];
        out[idx] = v;
    }
}

// ---------------------------------------------------------------------------
// K7: y+x diagonal pass (9 offsets, all multiples of 16 -> aligned float4),
// writes TRANSPOSED bf16 Ht[p][m] via LDS tile (for MFMA B-operand).
// ---------------------------------------------------------------------------
__global__ __launch_bounds__(256) void k_diag2t(const float* __restrict__ az,
                                                unsigned short* __restrict__ Ht) {
    __shared__ float T[64][65];
    int tid = threadIdx.x;
    int bi = blockIdx.y, bj = blockIdx.x;
    int m0 = bi * 64, p0 = bj * 64;
    int mx = bi >> 2, px = bj >> 2;
    int myb = 4 * (bi & 3), pyb = 4 * (bj & 3);
    int im = tid >> 4, jp = tid & 15;
    int pcol = pyb + (jp >> 2);

    float4 acc[4];
    #pragma unroll
    for (int g = 0; g < 4; g++) acc[g] = make_float4(0.f, 0.f, 0.f, 0.f);

    #pragma unroll
    for (int dx = -1; dx <= 1; dx++) {
        if (mx + dx < 0 || mx + dx > 15 || px + dx < 0 || px + dx > 15) continue;
        #pragma unroll
        for (int dy = -1; dy <= 1; dy++) {
            if (pcol + dy < 0 || pcol + dy > 15) continue;
            int D = dy * 16 + dx * 256;
            #pragma unroll
            for (int g = 0; g < 4; g++) {
                int myg = myb + g;
                if (myg + dy < 0 || myg + dy > 15) continue;
                float4 v = *(const float4*)&az[(size_t)(m0 + im + 16 * g + D) * L
                                               + p0 + jp * 4 + D];
                acc[g].x += v.x; acc[g].y += v.y; acc[g].z += v.z; acc[g].w += v.w;
            }
        }
    }
    #pragma unroll
    for (int g = 0; g < 4; g++) {
        T[im + 16 * g][jp * 4 + 0] = acc[g].x;
        T[im + 16 * g][jp * 4 + 1] = acc[g].y;
        T[im + 16 * g][jp * 4 + 2] = acc[g].z;
        T[im + 16 * g][jp * 4 + 3] = acc[g].w;
    }
    __syncthreads();
    int pr = tid >> 2, ms = (tid & 3) * 16;
    unsigned short ob[16];
    #pragma unroll
    for (int i = 0; i < 16; i++) ob[i] = f2bf(T[ms + i][pr]);
    uint4* dst = (uint4*)&Ht[(size_t)(p0 + pr) * L + m0 + ms];
    dst[0] = ((const uint4*)ob)[0];
    dst[1] = ((const uint4*)ob)[1];
}

// ---------------------------------------------------------------------------
// K8: MFMA R[c][p] = sum_m bg[c,m]*H[m,p], split-K=8.
// A: rows=c, k=m from bgh[c][m]; B: cols=p, k=m from Ht[p][m].
// ---------------------------------------------------------------------------
__global__ __launch_bounds__(256) void k_mm_mfma(const unsigned short* __restrict__ Ht,
                                                 const unsigned short* __restrict__ bgh,
                                                 float* __restrict__ part) {
    int tid = threadIdx.x;
    int w = tid >> 6, lane = tid & 63;
    int rr = lane & 15, kg = lane >> 4;
    int p0 = blockIdx.x * 64;
    int k0 = blockIdx.y * 512;

    f32x4 acc[4];
    #pragma unroll
    for (int pt = 0; pt < 4; pt++) { acc[pt][0] = 0.f; acc[pt][1] = 0.f; acc[pt][2] = 0.f; acc[pt][3] = 0.f; }

    for (int kk = 0; kk < 16; kk++) {
        int kb = k0 + kk * 32 + kg * 8;
        bf16x8 a = *(const bf16x8*)&bgh[(size_t)(w * 16 + rr) * L + kb];
        #pragma unroll
        for (int pt = 0; pt < 4; pt++) {
            bf16x8 b = *(const bf16x8*)&Ht[(size_t)(p0 + pt * 16 + rr) * L + kb];
            acc[pt] = __builtin_amdgcn_mfma_f32_16x16x32_bf16(a, b, acc[pt], 0, 0, 0);
        }
    }
    float* pp = part + (size_t)blockIdx.y * NC * L;
    #pragma unroll
    for (int pt = 0; pt < 4; pt++)
        #pragma unroll
        for (int r = 0; r < 4; r++)
            pp[(size_t)(w * 16 + kg * 4 + r) * L + p0 + pt * 16 + rr] = acc[pt][r];
}

// ---------------------------------------------------------------------------
// K9: reduce 8 partials + epilogue.
// ---------------------------------------------------------------------------
__global__ void k_epilogue(const float* __restrict__ part, const float* __restrict__ Tbox,
                           const float* __restrict__ mask_b, const float* __restrict__ fm_b,
                           float* __restrict__ out_b) {
    int idx = blockIdx.x * 256 + threadIdx.x;
    int p = idx & 4095;
    float s = 0.f;
    #pragma unroll
    for (int i = 0; i < 8; i++) s += part[(size_t)i * NC * L + idx];
    float m = mask_b[p];
    float r = (s + 1e-7f * Tbox[p]) * m * (1.f / 27.f);
    out_b[idx] = r + fm_b[idx] * (1.f - m);
}

// ---------------------------------------------------------------------------
extern "C" void kernel_launch(void* const* d_in, const int* in_sizes, int n_in,
                              void* d_out, int out_size, void* d_ws, size_t ws_size,
                              hipStream_t stream) {
    const float* fm = (const float*)d_in[0];
    const float* mask = (const float*)d_in[1];
    float* out = (float*)d_out;
    float* ws = (float*)d_ws;

    const size_t LL = (size_t)L * L;
    float* buf0 = ws;                              // Cz / a'z (f32, 67MB)
    float* buf1 = ws + LL;                         // logits (f32) then Ht(bf16)+partials
    unsigned short* Ht = (unsigned short*)buf1;    // 32MB, aliases dead logits
    float* part = buf1 + LL / 2;                   // 8MB, after Ht
    float* base = ws + 2 * LL;
    unsigned short* bgT = (unsigned short*)base;                    // BZ*L*NC bf16 = 2MB
    unsigned short* fmT = bgT + (size_t)BZ * L * NC;                // 2MB
    unsigned short* bgh = fmT + (size_t)BZ * L * NC;                // 2MB
    float* sfm  = (float*)(bgh + (size_t)BZ * L * NC);
    float* sbg  = sfm + (size_t)BZ * L;
    float* qbg  = sbg + (size_t)BZ * L;
    float* invn = qbg + (size_t)BZ * L;
    float* s2fm = invn + (size_t)BZ * L;
    float* colmax = s2fm + (size_t)BZ * L;
    float* csi    = colmax + L;
    float* Tarr   = csi + L;
    float* Tbox   = Tarr + L;
    float* pm     = Tbox + L;                      // 64*L each
    float* psum   = pm + 64 * (size_t)L;
    float* psumi  = psum + 64 * (size_t)L;

    k_prep<<<dim3(16, BZ), 256, 0, stream>>>(fm, mask, bgT, fmT, bgh, sfm, sbg, qbg);
    k_stats<<<BZ, 256, 0, stream>>>(sfm, sbg, qbg, invn, s2fm);

    for (int b = 0; b < BZ; b++) {
        const unsigned short* bgTb = bgT + (size_t)b * L * NC;
        const unsigned short* fmTb = fmT + (size_t)b * L * NC;
        const unsigned short* bghb = bgh + (size_t)b * NC * L;
        const float* invnb = invn + (size_t)b * L;
        const float* s2b = s2fm + (size_t)b * L;
        const float* maskb = mask + (size_t)b * L;
        const float* fmb = fm + (size_t)b * NC * L;
        float* outb = out + (size_t)b * NC * L;

        k_gram_mfma<<<dim3(64, 64), 256, 0, stream>>>(bgTb, fmTb, buf0);
        k_rowlogit<<<4096, 256, 0, stream>>>(buf0, buf1, s2b, invnb);
        k_colstat_part<<<dim3(4, 64), 256, 0, stream>>>(buf1, invnb, pm, psum, psumi);
        k_colstat_merge<<<16, 256, 0, stream>>>(pm, psum, psumi, colmax, csi, Tarr);
        k_tbox<<<1, 256, 0, stream>>>(Tarr, Tbox);
        k_sm_diagz<<<16384, 256, 0, stream>>>(buf1, buf0, colmax, csi, invnb);
        k_diag2t<<<dim3(64, 64), 256, 0, stream>>>(buf0, Ht);
        k_mm_mfma<<<dim3(64, 8), 256, 0, stream>>>(Ht, bghb, part);
        k_epilogue<<<1024, 256, 0, stream>>>(part, Tbox, maskb, fmb, outb);
    }
}

// Round 4
// 653.448 us; speedup vs baseline: 2.8118x; 1.4959x over previous
//
#include <hip/hip_runtime.h>
#include <hip/hip_bf16.h>
#include <math.h>

#define L 4096      // 16^3
#define NC 64
#define BZ 4
#define PS 17       // padded z-stride (bank-conflict-free)
#define PXD 272     // 16*PS

typedef __attribute__((ext_vector_type(8))) short bf16x8;
typedef __attribute__((ext_vector_type(4))) float f32x4;

__device__ inline unsigned short f2bf(float f) {
    unsigned int u = __float_as_uint(f);
    return (unsigned short)((u + 0x7fffu + ((u >> 16) & 1u)) >> 16);   // RNE
}
__device__ inline float bf2f(unsigned int u) { return __uint_as_float(u << 16); }
__device__ inline void unpack8(uint4 v, float* f) {
    f[0] = bf2f(v.x & 0xffffu); f[1] = bf2f(v.x >> 16);
    f[2] = bf2f(v.y & 0xffffu); f[3] = bf2f(v.y >> 16);
    f[4] = bf2f(v.z & 0xffffu); f[5] = bf2f(v.z >> 16);
    f[6] = bf2f(v.w & 0xffffu); f[7] = bf2f(v.w >> 16);
}
__device__ inline uint4 pack8(const float* f) {
    uint4 v;
    v.x = (unsigned)f2bf(f[0]) | ((unsigned)f2bf(f[1]) << 16);
    v.y = (unsigned)f2bf(f[2]) | ((unsigned)f2bf(f[3]) << 16);
    v.z = (unsigned)f2bf(f[4]) | ((unsigned)f2bf(f[5]) << 16);
    v.w = (unsigned)f2bf(f[6]) | ((unsigned)f2bf(f[7]) << 16);
    return v;
}

// ---------------------------------------------------------------------------
// f32 3-axis box filter helpers (k_stats / k_tbox only)
// ---------------------------------------------------------------------------
__device__ void box3_pad(float* A, float* B, int tid, float out[16]) {
    int x = tid >> 4, y = tid & 15;
    int base = x * PXD + y * PS;
    float t[16];
    {
        float line[16];
        #pragma unroll
        for (int z = 0; z < 16; z++) line[z] = A[base + z];
        #pragma unroll
        for (int z = 0; z < 16; z++) {
            float s = line[z];
            if (z > 0)  s += line[z - 1];
            if (z < 15) s += line[z + 1];
            t[z] = s;
        }
    }
    #pragma unroll
    for (int z = 0; z < 16; z++) B[base + z] = t[z];
    __syncthreads();
    #pragma unroll
    for (int z = 0; z < 16; z++) {
        float s = B[base + z];
        if (y > 0)  s += B[base - PS + z];
        if (y < 15) s += B[base + PS + z];
        t[z] = s;
    }
    __syncthreads();
    #pragma unroll
    for (int z = 0; z < 16; z++) A[base + z] = t[z];
    __syncthreads();
    #pragma unroll
    for (int z = 0; z < 16; z++) {
        float s = A[base + z];
        if (x > 0)  s += A[base - PXD + z];
        if (x < 15) s += A[base + PXD + z];
        out[z] = s;
    }
    __syncthreads();
}
__device__ inline void fill_pad(float* A, const float* __restrict__ g, int tid) {
    for (int i = tid; i < 4096; i += 256)
        A[(i >> 8) * PXD + ((i >> 4) & 15) * PS + (i & 15)] = g[i];
    __syncthreads();
}

// ---------------------------------------------------------------------------
// K1: bg=fm*(1-mask); bf16 copies bgT[l][c], fmT[p][c], bgh[c][p]; f32 sums.
// ---------------------------------------------------------------------------
__global__ void k_prep(const float* __restrict__ fm, const float* __restrict__ mask,
                       unsigned short* __restrict__ bgT, unsigned short* __restrict__ fmT,
                       unsigned short* __restrict__ bgh,
                       float* __restrict__ sfm, float* __restrict__ sbg,
                       float* __restrict__ qbg) {
    int b = blockIdx.y;
    int p = blockIdx.x * 256 + threadIdx.x;
    float m = mask[b * L + p];
    float w = 1.f - m;
    float s_f = 0.f, s_b = 0.f, q_b = 0.f;
    const float* fmb = fm + (size_t)b * NC * L + p;
    unsigned short* bghb = bgh + (size_t)b * NC * L + p;
    unsigned short tA[NC], tB[NC];
    #pragma unroll
    for (int c = 0; c < NC; c++) {
        float f = fmb[(size_t)c * L];
        float g = f * w;
        s_f += f; s_b += g; q_b += g * g;
        unsigned short gb = f2bf(g);
        tA[c] = gb;
        tB[c] = f2bf(f);
        bghb[(size_t)c * L] = gb;
    }
    unsigned short* bgTb = bgT + (size_t)b * L * NC + (size_t)p * NC;
    unsigned short* fmTb = fmT + (size_t)b * L * NC + (size_t)p * NC;
    #pragma unroll
    for (int i = 0; i < 8; i++) {
        ((uint4*)bgTb)[i] = ((const uint4*)tA)[i];
        ((uint4*)fmTb)[i] = ((const uint4*)tB)[i];
    }
    sfm[b * L + p] = s_f;
    sbg[b * L + p] = s_b;
    qbg[b * L + p] = q_b;
}

// ---------------------------------------------------------------------------
// K2: invn = rsqrt(box3(qbg)+2e-7*box3(sbg)+1728e-14); s2fm = box3(box3(sfm))
// ---------------------------------------------------------------------------
__global__ void k_stats(const float* __restrict__ sfm, const float* __restrict__ sbg,
                        const float* __restrict__ qbg,
                        float* __restrict__ invn, float* __restrict__ s2fm) {
    __shared__ float A[16 * PXD];
    __shared__ float Bf[16 * PXD];
    int b = blockIdx.x;
    int tid = threadIdx.x;
    int x = tid >> 4, y = tid & 15;
    float Q[16], Sb[16], r[16];

    fill_pad(A, qbg + b * L, tid);
    box3_pad(A, Bf, tid, Q);
    fill_pad(A, sbg + b * L, tid);
    box3_pad(A, Bf, tid, Sb);
    for (int z = 0; z < 16; z++) {
        float denom = Q[z] + 2e-7f * Sb[z] + 1.728e-11f;
        invn[b * L + x * 256 + y * 16 + z] = rsqrtf(denom);
    }
    fill_pad(A, sfm + b * L, tid);
    box3_pad(A, Bf, tid, r);
    int base = x * PXD + y * PS;
    #pragma unroll
    for (int z = 0; z < 16; z++) A[base + z] = r[z];
    __syncthreads();
    box3_pad(A, Bf, tid, r);
    for (int z = 0; z < 16; z++) s2fm[b * L + x * 256 + y * 16 + z] = r[z];
}

// ---------------------------------------------------------------------------
// K3: MFMA Gram + z-diag + z-box, bf16 output Czz in slot A.
// ---------------------------------------------------------------------------
__global__ __launch_bounds__(256) void k_gram(const unsigned short* __restrict__ bgT,
                                              const unsigned short* __restrict__ fmT,
                                              unsigned short* __restrict__ slab,
                                              size_t slotU, int b0) {
    int zi = blockIdx.z, b = b0 + zi;
    unsigned short* Czz = slab + (size_t)zi * slotU;
    const unsigned short* bgTb = bgT + (size_t)b * L * NC;
    const unsigned short* fmTb = fmT + (size_t)b * L * NC;
    __shared__ float Gs[64][65];
    __shared__ float D1[64][65];
    int tid = threadIdx.x;
    int l0 = blockIdx.y * 64, p0 = blockIdx.x * 64;
    int w = tid >> 6, lane = tid & 63;
    int rr = lane & 15, kg = lane >> 4;

    bf16x8 a0 = *(const bf16x8*)&bgTb[(size_t)(l0 + w * 16 + rr) * NC + kg * 8];
    bf16x8 a1 = *(const bf16x8*)&bgTb[(size_t)(l0 + w * 16 + rr) * NC + 32 + kg * 8];
    f32x4 acc[4];
    #pragma unroll
    for (int pt = 0; pt < 4; pt++) {
        bf16x8 bb0 = *(const bf16x8*)&fmTb[(size_t)(p0 + pt * 16 + rr) * NC + kg * 8];
        bf16x8 bb1 = *(const bf16x8*)&fmTb[(size_t)(p0 + pt * 16 + rr) * NC + 32 + kg * 8];
        f32x4 z; z[0] = 0.f; z[1] = 0.f; z[2] = 0.f; z[3] = 0.f;
        z = __builtin_amdgcn_mfma_f32_16x16x32_bf16(a0, bb0, z, 0, 0, 0);
        z = __builtin_amdgcn_mfma_f32_16x16x32_bf16(a1, bb1, z, 0, 0, 0);
        acc[pt] = z;
    }
    #pragma unroll
    for (int pt = 0; pt < 4; pt++)
        #pragma unroll
        for (int r = 0; r < 4; r++)
            Gs[w * 16 + kg * 4 + r][pt * 16 + rr] = acc[pt][r];
    __syncthreads();
    // diag-z
    for (int i = tid; i < 4096; i += 256) {
        int il = i >> 6, jp = i & 63;
        int lz = il & 15, pz = jp & 15;
        float v = Gs[il][jp];
        if (lz > 0 && pz > 0)   v += Gs[il - 1][jp - 1];
        if (lz < 15 && pz < 15) v += Gs[il + 1][jp + 1];
        D1[il][jp] = v;
    }
    __syncthreads();
    // box-z (over p) + bf16 write
    int row = tid >> 2, cg = (tid & 3) * 16;
    float o[16];
    #pragma unroll
    for (int k = 0; k < 16; k++) {
        int jp = cg + k;
        float v = D1[row][jp];
        if (k > 0)  v += D1[row][jp - 1];
        if (k < 15) v += D1[row][jp + 1];
        o[k] = v;
    }
    uint4* dst = (uint4*)&Czz[(size_t)(l0 + row) * L + p0 + cg];
    dst[0] = pack8(o);
    dst[1] = pack8(o + 8);
}

// ---------------------------------------------------------------------------
// K4: per l-row: diag-y/x (9 bf16 streams), box-y/x (one in-place LDS cube),
//     logit = (. + 1e-7*s2fm)*invn[l], E = exp(logit) (no-max), bf16 write.
// ---------------------------------------------------------------------------
__global__ __launch_bounds__(256) void k_rowE(unsigned short* __restrict__ slab,
                                              size_t slotU,
                                              const float* __restrict__ s2fm,
                                              const float* __restrict__ invn, int b0) {
    __shared__ float A[16 * PXD];
    int zi = blockIdx.z, b = b0 + zi;
    const unsigned short* Czz = slab + (size_t)zi * slotU;
    unsigned short* E = slab + (size_t)zi * slotU + (size_t)L * L;
    int bx = blockIdx.x;
    int l = (bx & 7) * 512 + (bx >> 3);         // XCD-chunked swizzle (bijective)
    int lx = l >> 8, ly = (l >> 4) & 15;
    int tid = threadIdx.x;
    int px = tid >> 4, py = tid & 15;
    float c[16];
    #pragma unroll
    for (int z = 0; z < 16; z++) c[z] = 0.f;

    #pragma unroll
    for (int dx = -1; dx <= 1; dx++) {
        if (lx + dx < 0 || lx + dx > 15 || px + dx < 0 || px + dx > 15) continue;
        #pragma unroll
        for (int dy = -1; dy <= 1; dy++) {
            if (ly + dy < 0 || ly + dy > 15 || py + dy < 0 || py + dy > 15) continue;
            const unsigned short* src = Czz + (size_t)(l + dy * 16 + dx * 256) * L
                                        + (px + dx) * 256 + (py + dy) * 16;
            float f[16];
            unpack8(((const uint4*)src)[0], f);
            unpack8(((const uint4*)src)[1], f + 8);
            #pragma unroll
            for (int z = 0; z < 16; z++) c[z] += f[z];
        }
    }
    int base = px * PXD + py * PS;
    #pragma unroll
    for (int z = 0; z < 16; z++) A[base + z] = c[z];
    __syncthreads();
    float t[16];
    #pragma unroll
    for (int z = 0; z < 16; z++) {          // box-y
        float s = A[base + z];
        if (py > 0)  s += A[base - PS + z];
        if (py < 15) s += A[base + PS + z];
        t[z] = s;
    }
    __syncthreads();
    #pragma unroll
    for (int z = 0; z < 16; z++) A[base + z] = t[z];
    __syncthreads();
    float inl = invn[(size_t)b * L + l];
    const float* s2 = s2fm + (size_t)b * L + px * 256 + py * 16;
    float o[16];
    #pragma unroll
    for (int z = 0; z < 16; z++) {          // box-x + logit + exp
        float s = A[base + z];
        if (px > 0)  s += A[base - PXD + z];
        if (px < 15) s += A[base + PXD + z];
        o[z] = __expf((s + 1e-7f * s2[z]) * inl);
    }
    uint4* dst = (uint4*)&E[(size_t)l * L + px * 256 + py * 16];
    dst[0] = pack8(o);
    dst[1] = pack8(o + 8);
}

// ---------------------------------------------------------------------------
// K5: column sums of E (no exp needed): partials [64][L] into slot A.
// ---------------------------------------------------------------------------
__global__ void k_colstat_part(unsigned short* __restrict__ slab, size_t slotU,
                               const float* __restrict__ invn, int b0) {
    int zi = blockIdx.z, b = b0 + zi;
    const unsigned short* E = slab + (size_t)zi * slotU + (size_t)L * L;
    float* ps = (float*)(slab + (size_t)zi * slotU);
    float* psi = ps + 64 * (size_t)L;
    int p8 = (blockIdx.x * 256 + threadIdx.x) * 8;
    int lc = blockIdx.y;
    const float* inv = invn + (size_t)b * L + lc * 64;
    float S[8], SI[8];
    #pragma unroll
    for (int j = 0; j < 8; j++) { S[j] = 0.f; SI[j] = 0.f; }
    const unsigned short* eb = E + (size_t)lc * 64 * L + p8;
    for (int i = 0; i < 64; i++) {
        uint4 v = *(const uint4*)(eb + (size_t)i * L);
        float f[8]; unpack8(v, f);
        float iv = inv[i];
        #pragma unroll
        for (int j = 0; j < 8; j++) { S[j] += f[j]; SI[j] += f[j] * iv; }
    }
    float4* d0 = (float4*)(ps + (size_t)lc * L + p8);
    float4* d1 = (float4*)(psi + (size_t)lc * L + p8);
    d0[0] = make_float4(S[0], S[1], S[2], S[3]);
    d0[1] = make_float4(S[4], S[5], S[6], S[7]);
    d1[0] = make_float4(SI[0], SI[1], SI[2], SI[3]);
    d1[1] = make_float4(SI[4], SI[5], SI[6], SI[7]);
}

__global__ void k_colstat_merge(unsigned short* __restrict__ slab, size_t slotU,
                                float* __restrict__ csi, float* __restrict__ Tarr, int b0) {
    int zi = blockIdx.z, b = b0 + zi;
    const float* ps = (const float*)(slab + (size_t)zi * slotU);
    const float* psi = ps + 64 * (size_t)L;
    int p = blockIdx.x * 256 + threadIdx.x;
    float s = 0.f, si = 0.f;
    for (int i = 0; i < 64; i++) { s += ps[(size_t)i * L + p]; si += psi[(size_t)i * L + p]; }
    float inv = 1.f / s;
    csi[(size_t)b * L + p] = inv;
    Tarr[(size_t)b * L + p] = si * inv;
}

__global__ void k_tbox(const float* __restrict__ Tarr, float* __restrict__ Tbox, int b0) {
    __shared__ float A[16 * PXD];
    __shared__ float Bf[16 * PXD];
    int b = b0 + blockIdx.z;
    int tid = threadIdx.x;
    fill_pad(A, Tarr + (size_t)b * L, tid);
    float res[16];
    box3_pad(A, Bf, tid, res);
    int x = tid >> 4, y = tid & 15;
    for (int z = 0; z < 16; z++) Tbox[(size_t)b * L + x * 256 + y * 16 + z] = res[z];
}

// ---------------------------------------------------------------------------
// K6: a'z[l,p] = sum_dz E[l+dz,p+dz]*csi[p+dz]*invn[l+dz]  (bf16 in/out)
// ---------------------------------------------------------------------------
__global__ void k_sm_diagz(unsigned short* __restrict__ slab, size_t slotU,
                           const float* __restrict__ csi, const float* __restrict__ invn,
                           int b0) {
    int zi = blockIdx.z, b = b0 + zi;
    const unsigned short* E = slab + (size_t)zi * slotU + (size_t)L * L;
    unsigned short* azz = slab + (size_t)zi * slotU;
    int line = blockIdx.x * 256 + threadIdx.x;    // 1M z-lines
    int l = line >> 8;
    int p0 = (line & 255) * 16;
    int lz = l & 15;
    bool hm = lz > 0, hp = lz < 15;

    float fc[16], fmv[16], fpv[16];
    const uint4* ec = (const uint4*)(E + (size_t)l * L + p0);
    unpack8(ec[0], fc); unpack8(ec[1], fc + 8);
    if (hm) {
        const uint4* em = (const uint4*)(E + (size_t)(l - 1) * L + p0);
        unpack8(em[0], fmv); unpack8(em[1], fmv + 8);
    }
    if (hp) {
        const uint4* ep = (const uint4*)(E + (size_t)(l + 1) * L + p0);
        unpack8(ep[0], fpv); unpack8(ep[1], fpv + 8);
    }
    float cs[16];
    const float4* cp = (const float4*)(csi + (size_t)b * L + p0);
    #pragma unroll
    for (int q = 0; q < 4; q++) {
        float4 v = cp[q];
        cs[q * 4] = v.x; cs[q * 4 + 1] = v.y; cs[q * 4 + 2] = v.z; cs[q * 4 + 3] = v.w;
    }
    float inl = invn[(size_t)b * L + l];
    float inlm = hm ? invn[(size_t)b * L + l - 1] : 0.f;
    float inlp = hp ? invn[(size_t)b * L + l + 1] : 0.f;
    float o[16];
    #pragma unroll
    for (int z = 0; z < 16; z++) {
        float v = fc[z] * cs[z] * inl;
        if (hm && z > 0)  v += fmv[z - 1] * cs[z - 1] * inlm;
        if (hp && z < 15) v += fpv[z + 1] * cs[z + 1] * inlp;
        o[z] = v;
    }
    uint4* dst = (uint4*)&azz[(size_t)l * L + p0];
    dst[0] = pack8(o);
    dst[1] = pack8(o + 8);
}

// ---------------------------------------------------------------------------
// K7: diag-y/x on a'z (9 bf16 streams) + transpose -> Ht[p][m] bf16 (slot B)
// ---------------------------------------------------------------------------
__global__ __launch_bounds__(256) void k_diag2t(unsigned short* __restrict__ slab,
                                                size_t slotU) {
    __shared__ float T[64][65];
    int zi = blockIdx.z;
    const unsigned short* azz = slab + (size_t)zi * slotU;
    unsigned short* Ht = slab + (size_t)zi * slotU + (size_t)L * L;
    int tid = threadIdx.x;
    int bi = blockIdx.y, bj = blockIdx.x;
    int m0 = bi * 64, p0 = bj * 64;
    int mx = bi >> 2, px = bj >> 2;
    int myb = 4 * (bi & 3), pyb = 4 * (bj & 3);
    int im = tid >> 3;              // 0..31
    int jp8 = (tid & 7) * 8;        // 8-col group (all same py)
    int pcol = pyb + (jp8 >> 4);

    float acc[2][8];
    #pragma unroll
    for (int g = 0; g < 2; g++)
        #pragma unroll
        for (int j = 0; j < 8; j++) acc[g][j] = 0.f;

    #pragma unroll
    for (int dx = -1; dx <= 1; dx++) {
        if (mx + dx < 0 || mx + dx > 15 || px + dx < 0 || px + dx > 15) continue;
        #pragma unroll
        for (int dy = -1; dy <= 1; dy++) {
            if (pcol + dy < 0 || pcol + dy > 15) continue;
            int D = dy * 16 + dx * 256;
            #pragma unroll
            for (int g = 0; g < 2; g++) {
                int m = im + 32 * g;
                int my = myb + (m >> 4);
                if (my + dy < 0 || my + dy > 15) continue;
                uint4 v = *(const uint4*)(azz + (size_t)(m0 + m + D) * L + p0 + jp8 + D);
                float f[8]; unpack8(v, f);
                #pragma unroll
                for (int j = 0; j < 8; j++) acc[g][j] += f[j];
            }
        }
    }
    #pragma unroll
    for (int g = 0; g < 2; g++)
        #pragma unroll
        for (int j = 0; j < 8; j++) T[im + 32 * g][jp8 + j] = acc[g][j];
    __syncthreads();
    int pr = tid >> 2, ms = (tid & 3) * 16;
    float o[16];
    #pragma unroll
    for (int i = 0; i < 16; i++) o[i] = T[ms + i][pr];
    uint4* dst = (uint4*)&Ht[(size_t)(p0 + pr) * L + m0 + ms];
    dst[0] = pack8(o);
    dst[1] = pack8(o + 8);
}

// ---------------------------------------------------------------------------
// K8: MFMA R[c][p] = sum_m bg[c,m]*H[m,p], split-K=8 -> part (f32, slot A)
// ---------------------------------------------------------------------------
__global__ __launch_bounds__(256) void k_mm(unsigned short* __restrict__ slab, size_t slotU,
                                            const unsigned short* __restrict__ bgh, int b0) {
    int zi = blockIdx.z, b = b0 + zi;
    const unsigned short* Ht = slab + (size_t)zi * slotU + (size_t)L * L;
    float* part = (float*)(slab + (size_t)zi * slotU);
    const unsigned short* bghb = bgh + (size_t)b * NC * L;
    int tid = threadIdx.x;
    int w = tid >> 6, lane = tid & 63;
    int rr = lane & 15, kg = lane >> 4;
    int p0 = blockIdx.x * 64;
    int k0 = blockIdx.y * 512;

    f32x4 acc[4];
    #pragma unroll
    for (int pt = 0; pt < 4; pt++) { acc[pt][0] = 0.f; acc[pt][1] = 0.f; acc[pt][2] = 0.f; acc[pt][3] = 0.f; }

    for (int kk = 0; kk < 16; kk++) {
        int kb = k0 + kk * 32 + kg * 8;
        bf16x8 a = *(const bf16x8*)&bghb[(size_t)(w * 16 + rr) * L + kb];
        #pragma unroll
        for (int pt = 0; pt < 4; pt++) {
            bf16x8 bb = *(const bf16x8*)&Ht[(size_t)(p0 + pt * 16 + rr) * L + kb];
            acc[pt] = __builtin_amdgcn_mfma_f32_16x16x32_bf16(a, bb, acc[pt], 0, 0, 0);
        }
    }
    float* pp = part + (size_t)blockIdx.y * NC * L;
    #pragma unroll
    for (int pt = 0; pt < 4; pt++)
        #pragma unroll
        for (int r = 0; r < 4; r++)
            pp[(size_t)(w * 16 + kg * 4 + r) * L + p0 + pt * 16 + rr] = acc[pt][r];
}

// ---------------------------------------------------------------------------
// K9: reduce 8 partials + epilogue (float4).
// ---------------------------------------------------------------------------
__global__ void k_epilogue(unsigned short* __restrict__ slab, size_t slotU,
                           const float* __restrict__ Tbox, const float* __restrict__ mask,
                           const float* __restrict__ fm, float* __restrict__ out, int b0) {
    int zi = blockIdx.z, b = b0 + zi;
    const float* part = (const float*)(slab + (size_t)zi * slotU);
    int idx4 = (blockIdx.x * 256 + threadIdx.x) * 4;
    int p = idx4 & 4095;
    float4 s = make_float4(0.f, 0.f, 0.f, 0.f);
    #pragma unroll
    for (int i = 0; i < 8; i++) {
        float4 v = *(const float4*)(part + (size_t)i * NC * L + idx4);
        s.x += v.x; s.y += v.y; s.z += v.z; s.w += v.w;
    }
    float4 tb = *(const float4*)(Tbox + (size_t)b * L + p);
    float4 mk = *(const float4*)(mask + (size_t)b * L + p);
    float4 fv = *(const float4*)(fm + (size_t)b * NC * L + idx4);
    float4 o;
    o.x = (s.x + 1e-7f * tb.x) * mk.x * (1.f / 27.f) + fv.x * (1.f - mk.x);
    o.y = (s.y + 1e-7f * tb.y) * mk.y * (1.f / 27.f) + fv.y * (1.f - mk.y);
    o.z = (s.z + 1e-7f * tb.z) * mk.z * (1.f / 27.f) + fv.z * (1.f - mk.z);
    o.w = (s.w + 1e-7f * tb.w) * mk.w * (1.f / 27.f) + fv.w * (1.f - mk.w);
    *(float4*)(out + (size_t)b * NC * L + idx4) = o;
}

// ---------------------------------------------------------------------------
extern "C" void kernel_launch(void* const* d_in, const int* in_sizes, int n_in,
                              void* d_out, int out_size, void* d_ws, size_t ws_size,
                              hipStream_t stream) {
    const float* fm = (const float*)d_in[0];
    const float* mask = (const float*)d_in[1];
    float* out = (float*)d_out;

    // fixed region
    unsigned short* bgT = (unsigned short*)d_ws;               // BZ*L*NC
    unsigned short* fmT = bgT + (size_t)BZ * L * NC;
    unsigned short* bgh = fmT + (size_t)BZ * L * NC;
    float* sfm  = (float*)(bgh + (size_t)BZ * L * NC);
    float* sbg  = sfm + (size_t)BZ * L;
    float* qbg  = sbg + (size_t)BZ * L;
    float* invn = qbg + (size_t)BZ * L;
    float* s2fm = invn + (size_t)BZ * L;
    float* csi  = s2fm + (size_t)BZ * L;
    float* Tarr = csi + (size_t)BZ * L;
    float* Tbox = Tarr + (size_t)BZ * L;
    unsigned short* slab = (unsigned short*)(Tbox + (size_t)BZ * L);

    const size_t slotU = 2 * (size_t)L * L;                    // ushorts per slot (67.1MB)
    size_t fixedBytes = (char*)slab - (char*)d_ws;
    size_t avail = ws_size > fixedBytes ? ws_size - fixedBytes : 0;
    int ns = (int)(avail / (slotU * sizeof(unsigned short)));
    if (ns >= 4) ns = 4; else if (ns >= 2) ns = 2; else ns = 1;

    k_prep<<<dim3(16, BZ), 256, 0, stream>>>(fm, mask, bgT, fmT, bgh, sfm, sbg, qbg);
    k_stats<<<BZ, 256, 0, stream>>>(sfm, sbg, qbg, invn, s2fm);

    for (int b0 = 0; b0 < BZ; b0 += ns) {
        int nb = (BZ - b0) < ns ? (BZ - b0) : ns;
        k_gram<<<dim3(64, 64, nb), 256, 0, stream>>>(bgT, fmT, slab, slotU, b0);
        k_rowE<<<dim3(4096, 1, nb), 256, 0, stream>>>(slab, slotU, s2fm, invn, b0);
        k_colstat_part<<<dim3(2, 64, nb), 256, 0, stream>>>(slab, slotU, invn, b0);
        k_colstat_merge<<<dim3(16, 1, nb), 256, 0, stream>>>(slab, slotU, csi, Tarr, b0);
        k_tbox<<<dim3(1, 1, nb), 256, 0, stream>>>(Tarr, Tbox, b0);
        k_sm_diagz<<<dim3(4096, 1, nb), 256, 0, stream>>>(slab, slotU, csi, invn, b0);
        k_diag2t<<<dim3(64, 64, nb), 256, 0, stream>>>(slab, slotU);
        k_mm<<<dim3(64, 8, nb), 256, 0, stream>>>(slab, slotU, bgh, b0);
        k_epilogue<<<dim3(256, 1, nb), 256, 0, stream>>>(slab, slotU, Tbox, mask, fm, out, b0);
    }
}